// Round 2
// baseline (165.718 us; speedup 1.0000x reference)
//
#include <hip/hip_runtime.h>
#include <hip/hip_bf16.h>

#define CRF_B 1024
#define CRF_T 512
#define CRF_C 32

// One wave (64 lanes) = one batch row. lane = ks*32 + j (ks = k-half, j = tag).
// State: r[k] = scaled prob exp(alpha[k] - C) in LDS (double-buffered), plus
// integer exponent e of r[0] for frexp/ldexp renormalization.
// Recurrence (no log/exp on the critical path):
//   S_j     = sum_k E[j,k] * r_prev[k]          (16 FMA per lane + 1 shfl_xor)
//   S_norm  = ldexp(S_j, -e_prev)
//   r_new_j = S_norm * fx_j,  fx_j = exp(x[t,j]) (precomputed 1 step early)
// Output (off-chain): alpha[t,j] = C_t + x[t,j] + log(S_norm),
//   C_t = C_{t-1} + e_prev * ln2 (per-lane scalar, exact integer exponent sum).
__global__ __launch_bounds__(64) void crf_fwd_kernel(
    const float* __restrict__ x,      // [B, T, C]
    const float* __restrict__ trans,  // [C, C]  trans[j][k]
    const float* __restrict__ orig,   // [C]
    float* __restrict__ out)          // [T, B, C]
{
    const int lane = threadIdx.x;
    const int ks   = lane >> 5;   // which k-half this lane sums
    const int j    = lane & 31;   // tag index
    const int b    = blockIdx.x;

    __shared__ float rbuf[2][32];
    __shared__ int   ebuf[2];

    // E[j][ks*16 + i], exponentiated
    float E[16];
    {
        const float4* trow = (const float4*)(trans + j * CRF_C + ks * 16);
        #pragma unroll
        for (int q = 0; q < 4; ++q) {
            float4 v = trow[q];
            E[4*q+0] = __expf(v.x);
            E[4*q+1] = __expf(v.y);
            E[4*q+2] = __expf(v.z);
            E[4*q+3] = __expf(v.w);
        }
    }

    const float* xb = x + (size_t)b * CRF_T * CRF_C + j;  // stride CRF_C per t

    // ---- t = 0 ----
    float a0 = xb[0] + orig[j];
    if (ks == 0) out[(size_t)b * CRF_C + j] = a0;
    float r0 = __expf(a0);                 // |a0| small, safe unshifted
    int e0;  (void)frexpf(r0, &e0);
    if (ks == 0) rbuf[0][j] = r0;
    if (lane == 0) ebuf[0] = e0;

    // emission prefetch pipeline, depth 6 (t = 1..6)
    float x0 = xb[1 * CRF_C];
    float x1 = xb[2 * CRF_C];
    float x2 = xb[3 * CRF_C];
    float x3 = xb[4 * CRF_C];
    float x4 = xb[5 * CRF_C];
    float x5 = xb[6 * CRF_C];

    float Csum = 0.0f;
    __syncthreads();

    for (int t = 1; t < CRF_T; ++t) {
        const int p = (t - 1) & 1;

        // consume head of prefetch pipe; refill tail (clamped index)
        float xt = x0;
        float fx = __expf(xt);             // off critical path
        x0 = x1; x1 = x2; x2 = x3; x3 = x4; x4 = x5;
        int tl = t + 6; if (tl > CRF_T - 1) tl = CRF_T - 1;
        x5 = xb[tl * CRF_C];

        int eprev = ebuf[p];

        // S_part = sum over this lane's 16 k's
        const float4* rp = (const float4*)(rbuf[p] + ks * 16);
        float s0 = 0.f, s1 = 0.f, s2 = 0.f, s3 = 0.f;
        #pragma unroll
        for (int q = 0; q < 4; ++q) {
            float4 P = rp[q];
            s0 = fmaf(P.x, E[4*q+0], s0);
            s1 = fmaf(P.y, E[4*q+1], s1);
            s2 = fmaf(P.z, E[4*q+2], s2);
            s3 = fmaf(P.w, E[4*q+3], s3);
        }
        float Sp = (s0 + s1) + (s2 + s3);
        float S  = Sp + __shfl_xor(Sp, 32);      // combine the two k-halves

        float Sn   = ldexpf(S, -eprev);          // renormalize
        float rnew = Sn * fx;                    // next state (chain ends here)

        int en; (void)frexpf(rnew, &en);         // only lane 0's value used

        // off-chain output
        Csum += (float)eprev * 0.69314718055994530942f;
        float al = Csum + xt + __logf(Sn);

        if (ks == 0) {
            rbuf[p ^ 1][j] = rnew;
            out[((size_t)t * CRF_B + b) * CRF_C + j] = al;
        }
        if (lane == 0) ebuf[p ^ 1] = en;

        __syncthreads();
    }
}

extern "C" void kernel_launch(void* const* d_in, const int* in_sizes, int n_in,
                              void* d_out, int out_size, void* d_ws, size_t ws_size,
                              hipStream_t stream) {
    const float* pad_x = (const float*)d_in[0];
    const float* trans = (const float*)d_in[1];
    const float* orig  = (const float*)d_in[2];
    float* out = (float*)d_out;

    crf_fwd_kernel<<<dim3(CRF_B), dim3(64), 0, stream>>>(pad_x, trans, orig, out);
}

// Round 3
// 153.096 us; speedup vs baseline: 1.0824x; 1.0824x over previous
//
#include <hip/hip_runtime.h>
#include <hip/hip_bf16.h>

#define CRF_B 1024
#define CRF_T 512
#define CRF_C 32

// One wave = 2 batch rows: lanes 0-31 -> row 2*blk, lanes 32-63 -> row 2*blk+1.
// Invariant at top of step t:
//   pbuf[(t-1)&1][bl][k] = exp(alpha_{t-1}[k] - sigma),  sigma = alpha_{t-2}[0]
//   a0 = alpha_{t-1}[0]
// Step t:
//   S_j   = sum_k E[j,k] * p[k]                  (32 FMA, on-chain)
//   alpha_t[j] = x_t[j] + sigma + log(S_j)       (off-chain, store only)
//   p_new[j]   = S_j * f_j,  f_j = exp(x_t[j] + sigma - a0)  (f precomputed
//                parallel to the LDS read -> only 1 mul on-chain after S)
// sigma/a0 propagate via v_readlane (SGPR), not LDS.
__global__ __launch_bounds__(64) void crf_fwd_kernel(
    const float* __restrict__ x,      // [B, T, C]
    const float* __restrict__ trans,  // [C, C]
    const float* __restrict__ orig,   // [C]
    float* __restrict__ out)          // [T, B, C]
{
    const int lane = threadIdx.x;
    const int bl   = lane >> 5;
    const int j    = lane & 31;
    const int b    = blockIdx.x * 2 + bl;

    __shared__ float pbuf[2][2][32];

    // E[j][k] = exp(trans[j][k]) — per-lane row in registers
    float E[32];
    {
        const float4* trow = (const float4*)(trans + j * CRF_C);
        #pragma unroll
        for (int q = 0; q < 8; ++q) {
            float4 v = trow[q];
            E[4*q+0] = __expf(v.x);
            E[4*q+1] = __expf(v.y);
            E[4*q+2] = __expf(v.z);
            E[4*q+3] = __expf(v.w);
        }
    }

    const float* xb = x + ((size_t)b * CRF_T) * CRF_C + j;

    // ---- t = 0 ----
    float a = xb[0] + orig[j];
    out[(size_t)b * CRF_C + j] = a;

    int ia = __float_as_int(a);
    int rA = __builtin_amdgcn_readlane(ia, 0);
    int rB = __builtin_amdgcn_readlane(ia, 32);
    float a0 = __int_as_float(bl == 0 ? rA : rB);   // alpha_0[0] for this half

    pbuf[0][bl][j] = __expf(a - a0);   // branchless: each lane writes its own

    float sigma = a0;          // shift used to normalize p_0
    float sm_a0 = 0.0f;        // sigma - a0 (both = alpha_0[0] at t=1)

    // emission prefetch pipeline, depth 4
    float x0 = xb[1 * CRF_C];
    float x1 = xb[2 * CRF_C];
    float x2 = xb[3 * CRF_C];
    float x3 = xb[4 * CRF_C];

    float* outp = out + (size_t)CRF_B * CRF_C + (size_t)b * CRF_C + j;

    __syncthreads();

    for (int t = 1; t < CRF_T; ++t) {
        // rotate prefetch pipe; refill tail (clamped)
        float xt = x0;
        x0 = x1; x1 = x2; x2 = x3;
        int tl = t + 4; if (tl > CRF_T - 1) tl = CRF_T - 1;
        x3 = xb[tl * CRF_C];

        // f off the LDS chain: everything known at loop entry
        float f = __expf(xt + sm_a0);

        // S_j = sum_k p[k] * E[j][k]  (broadcast LDS reads, conflict-free)
        const float4* rp = (const float4*)pbuf[(t - 1) & 1][bl];
        float s0 = 0.f, s1 = 0.f, s2 = 0.f, s3 = 0.f;
        #pragma unroll
        for (int q = 0; q < 8; ++q) {
            float4 P = rp[q];
            s0 = fmaf(P.x, E[4*q+0], s0);
            s1 = fmaf(P.y, E[4*q+1], s1);
            s2 = fmaf(P.z, E[4*q+2], s2);
            s3 = fmaf(P.w, E[4*q+3], s3);
        }
        float S = (s0 + s1) + (s2 + s3);

        // critical-path end: one mul, one ds_write
        pbuf[t & 1][bl][j] = S * f;

        // off-chain output
        float anew = xt + sigma + __logf(S);
        *outp = anew;
        outp += (size_t)CRF_B * CRF_C;

        // propagate shifts via readlane (SGPR, no LDS)
        int ian = __float_as_int(anew);
        int nA = __builtin_amdgcn_readlane(ian, 0);
        int nB = __builtin_amdgcn_readlane(ian, 32);
        float a0n = __int_as_float(bl == 0 ? nA : nB);

        sm_a0 = a0 - a0n;   // (sigma' - a0') for next step
        sigma = a0;
        a0    = a0n;

        __syncthreads();
    }
}

extern "C" void kernel_launch(void* const* d_in, const int* in_sizes, int n_in,
                              void* d_out, int out_size, void* d_ws, size_t ws_size,
                              hipStream_t stream) {
    const float* pad_x = (const float*)d_in[0];
    const float* trans = (const float*)d_in[1];
    const float* orig  = (const float*)d_in[2];
    float* out = (float*)d_out;

    crf_fwd_kernel<<<dim3(CRF_B / 2), dim3(64), 0, stream>>>(pad_x, trans, orig, out);
}